// Round 12
// baseline (155.310 us; speedup 1.0000x reference)
//
#include <hip/hip_runtime.h>
#include <hip/hip_fp16.h>

#define LN_EPS 1e-5f

static __device__ __forceinline__ float4 f4zero() { return make_float4(0.f, 0.f, 0.f, 0.f); }

// ---------------------------------------------------------------------------
// K1: feat[N][32](fp16) = X[N][128] @ Wf[128][32] + bf ; skill[N] = (int)X[n][0]
// (verified R10/R11 version, unchanged.)
// ---------------------------------------------------------------------------
__global__ __launch_bounds__(256, 4) void k_feat(
    const float* __restrict__ X, const float* __restrict__ Wf,
    const float* __restrict__ bf, __half* __restrict__ feat,
    int* __restrict__ skill, int N)
{
    __shared__ float Wl[128 * 32];
    for (int i = threadIdx.x; i < 128 * 32; i += 256) Wl[i] = Wf[i];
    __syncthreads();

    const int gid  = blockIdx.x * 256 + threadIdx.x;
    const int r0   = gid >> 3;         // thread handles rows r0 and r0+half
    const int dg   = gid & 7;          // dims 4*dg .. 4*dg+3
    const int half = (N + 1) >> 1;
    if (r0 >= half) return;
    const int r1 = r0 + half;
    const bool v1 = (r1 < N);

    const float4* __restrict__ X0 = (const float4*)X + (size_t)r0 * 32;
    const float4* __restrict__ X1 = (const float4*)X + (size_t)(v1 ? r1 : r0) * 32;
    const float4* __restrict__ W4 = (const float4*)Wl;

    const float4 bias = *(const float4*)(bf + 4 * dg);
    float4 acc0 = bias, acc1 = bias;

    float4 xv0 = X0[0];
    float4 xv1 = X1[0];
    if (dg == 0) {
        skill[r0] = (int)xv0.x;                 // trunc == astype(int32)
        if (v1) skill[r1] = (int)xv1.x;
    }

    #pragma unroll 2
    for (int f4 = 0; f4 < 32; ++f4) {
        float4 nx0 = f4zero(), nx1 = f4zero();
        if (f4 < 31) { nx0 = X0[f4 + 1]; nx1 = X1[f4 + 1]; }

        const float4 w0 = W4[(4 * f4 + 0) * 8 + dg];
        const float4 w1 = W4[(4 * f4 + 1) * 8 + dg];
        const float4 w2 = W4[(4 * f4 + 2) * 8 + dg];
        const float4 w3 = W4[(4 * f4 + 3) * 8 + dg];

        acc0.x = fmaf(xv0.x, w0.x, acc0.x);
        acc0.y = fmaf(xv0.x, w0.y, acc0.y);
        acc0.z = fmaf(xv0.x, w0.z, acc0.z);
        acc0.w = fmaf(xv0.x, w0.w, acc0.w);
        acc1.x = fmaf(xv1.x, w0.x, acc1.x);
        acc1.y = fmaf(xv1.x, w0.y, acc1.y);
        acc1.z = fmaf(xv1.x, w0.z, acc1.z);
        acc1.w = fmaf(xv1.x, w0.w, acc1.w);
        acc0.x = fmaf(xv0.y, w1.x, acc0.x);
        acc0.y = fmaf(xv0.y, w1.y, acc0.y);
        acc0.z = fmaf(xv0.y, w1.z, acc0.z);
        acc0.w = fmaf(xv0.y, w1.w, acc0.w);
        acc1.x = fmaf(xv1.y, w1.x, acc1.x);
        acc1.y = fmaf(xv1.y, w1.y, acc1.y);
        acc1.z = fmaf(xv1.y, w1.z, acc1.z);
        acc1.w = fmaf(xv1.y, w1.w, acc1.w);
        acc0.x = fmaf(xv0.z, w2.x, acc0.x);
        acc0.y = fmaf(xv0.z, w2.y, acc0.y);
        acc0.z = fmaf(xv0.z, w2.z, acc0.z);
        acc0.w = fmaf(xv0.z, w2.w, acc0.w);
        acc1.x = fmaf(xv1.z, w2.x, acc1.x);
        acc1.y = fmaf(xv1.z, w2.y, acc1.y);
        acc1.z = fmaf(xv1.z, w2.z, acc1.z);
        acc1.w = fmaf(xv1.z, w2.w, acc1.w);
        acc0.x = fmaf(xv0.w, w3.x, acc0.x);
        acc0.y = fmaf(xv0.w, w3.y, acc0.y);
        acc0.z = fmaf(xv0.w, w3.z, acc0.z);
        acc0.w = fmaf(xv0.w, w3.w, acc0.w);
        acc1.x = fmaf(xv1.w, w3.x, acc1.x);
        acc1.y = fmaf(xv1.w, w3.y, acc1.y);
        acc1.z = fmaf(xv1.w, w3.z, acc1.z);
        acc1.w = fmaf(xv1.w, w3.w, acc1.w);

        xv0 = nx0; xv1 = nx1;
    }

    union { __half2 h2[2]; uint2 u; } cv;
    cv.h2[0] = __float22half2_rn(make_float2(acc0.x, acc0.y));
    cv.h2[1] = __float22half2_rn(make_float2(acc0.z, acc0.w));
    *(uint2*)(feat + (size_t)r0 * 32 + 4 * dg) = cv.u;
    if (v1) {
        cv.h2[0] = __float22half2_rn(make_float2(acc1.x, acc1.y));
        cv.h2[1] = __float22half2_rn(make_float2(acc1.z, acc1.w));
        *(uint2*)(feat + (size_t)r1 * 32 + 4 * dg) = cv.u;
    }
}

// ---------------------------------------------------------------------------
// K2: fused per-sample pipeline, 4 threads/row (verified R11 structure) with
// two latency levers: (a) launch_bounds(512,8) -> 4 blocks/CU = 32 waves/CU
// (was 24); VGPR cap 64, peak live ~50 fits (NOT a R7 repeat). (b) node ids
// loaded once per row (sub-lane 0) + shfl broadcast, and all 5 feat uint4
// gathers issued into a register batch BEFORE summation: 5 independent HBM
// loads in flight per thread (gathers always L2-cold -- the harness's 268MB
// poison sweep flushes caches every iteration).
// ---------------------------------------------------------------------------
__global__ __launch_bounds__(512, 8) void k_fused(
    const __half* __restrict__ feat, const int* __restrict__ skill,
    const int* __restrict__ rnodes, const int* __restrict__ ridx,
    const int* __restrict__ dst_ids,
    const float* __restrict__ w_struct, const float* __restrict__ b_struct,
    const float* __restrict__ ln_g, const float* __restrict__ ln_b,
    const float* __restrict__ Wg, const float* __restrict__ b_gcn,
    const float* __restrict__ Wo, const float* __restrict__ b_out,
    float* __restrict__ out, int B)
{
    __shared__ float Wgl[32 * 32];
    __shared__ float Wol[32 * 32];
    __shared__ float xwT[32][101];
    __shared__ float pooled[32];

    const int t = threadIdx.x, b = blockIdx.x;

    for (int i = t; i < 1024; i += 512) { Wgl[i] = Wg[i]; Wol[i] = Wo[i]; }

    const int l    = t >> 2;           // row 0..127 (active < 100)
    const int dg2  = t & 3;            // dims 8*dg2 .. 8*dg2+7
    const int lane = t & 63;
    const bool act = (l < 100);
    const int qa = 2 * dg2, qb = 2 * dg2 + 1;

    const int* __restrict__ rb = ridx + b * 5;
    const int cskill = skill[dst_ids[b]];

    int n0 = 0, simc = 0;
    float4 a0 = f4zero(), a1 = f4zero();

    if (act) {
        // row leader (sub-lane 0) loads the 5 node ids; broadcast via shfl
        int nodes[5];
        if (dg2 == 0) {
            #pragma unroll
            for (int r = 0; r < 5; ++r) nodes[r] = rnodes[(size_t)rb[r] * 100 + l];
        }
        #pragma unroll
        for (int r = 0; r < 5; ++r) nodes[r] = __shfl(nodes[r], lane & ~3, 64);
        n0 = nodes[0];

        if (dg2 == 0) {
            #pragma unroll
            for (int r = 0; r < 5; ++r)
                simc += (skill[nodes[r]] == cskill) ? 1 : 0;
        }

        // issue ALL 5 feat gathers before consuming any (5 loads in flight)
        uint4 raw[5];
        #pragma unroll
        for (int r = 0; r < 5; ++r)
            raw[r] = *(const uint4*)(feat + (size_t)nodes[r] * 32 + 8 * dg2);

        #pragma unroll
        for (int r = 0; r < 5; ++r) {
            const float2 f0 = __half22float2(*(const __half2*)&raw[r].x);
            const float2 f1 = __half22float2(*(const __half2*)&raw[r].y);
            const float2 f2 = __half22float2(*(const __half2*)&raw[r].z);
            const float2 f3 = __half22float2(*(const __half2*)&raw[r].w);
            a0.x += f0.x; a0.y += f0.y; a0.z += f1.x; a0.w += f1.y;
            a1.x += f2.x; a1.y += f2.y; a1.z += f3.x; a1.w += f3.y;
        }
    }

    // barrier (covers Wgl/Wol staging) + per-b valid count in one op
    const int valid = __syncthreads_count(act && dg2 == 0 && n0 > 0);

    float4 o0 = f4zero(), o1 = f4zero();
    if (act) {
        simc = __shfl(simc, lane & ~3, 64);    // broadcast from sub-lane 0
        const float simf = (float)simc * 0.2f;
        {
            const float4 wsA = ((const float4*)w_struct)[qa];
            const float4 wsB = ((const float4*)w_struct)[qb];
            const float4 bsA = ((const float4*)b_struct)[qa];
            const float4 bsB = ((const float4*)b_struct)[qb];
            a0.x = fmaf(a0.x, 0.2f, fmaf(simf, wsA.x, bsA.x));
            a0.y = fmaf(a0.y, 0.2f, fmaf(simf, wsA.y, bsA.y));
            a0.z = fmaf(a0.z, 0.2f, fmaf(simf, wsA.z, bsA.z));
            a0.w = fmaf(a0.w, 0.2f, fmaf(simf, wsA.w, bsA.w));
            a1.x = fmaf(a1.x, 0.2f, fmaf(simf, wsB.x, bsB.x));
            a1.y = fmaf(a1.y, 0.2f, fmaf(simf, wsB.y, bsB.y));
            a1.z = fmaf(a1.z, 0.2f, fmaf(simf, wsB.z, bsB.z));
            a1.w = fmaf(a1.w, 0.2f, fmaf(simf, wsB.w, bsB.w));
        }

        // LayerNorm over D=32 = 4 lanes x 8 dims (two-pass, biased var)
        float part = a0.x + a0.y + a0.z + a0.w + a1.x + a1.y + a1.z + a1.w;
        part += __shfl_xor(part, 1);
        part += __shfl_xor(part, 2);
        const float mu = part * (1.f / 32.f);
        float dx, sq;
        dx = a0.x - mu; sq  = dx * dx;
        dx = a0.y - mu; sq  = fmaf(dx, dx, sq);
        dx = a0.z - mu; sq  = fmaf(dx, dx, sq);
        dx = a0.w - mu; sq  = fmaf(dx, dx, sq);
        dx = a1.x - mu; sq  = fmaf(dx, dx, sq);
        dx = a1.y - mu; sq  = fmaf(dx, dx, sq);
        dx = a1.z - mu; sq  = fmaf(dx, dx, sq);
        dx = a1.w - mu; sq  = fmaf(dx, dx, sq);
        sq += __shfl_xor(sq, 1);
        sq += __shfl_xor(sq, 2);
        const float rs = rsqrtf(sq * (1.f / 32.f) + LN_EPS);

        float4 y0, y1;
        {
            const float4 gA = ((const float4*)ln_g)[qa];
            const float4 gB = ((const float4*)ln_g)[qb];
            const float4 bA = ((const float4*)ln_b)[qa];
            const float4 bB = ((const float4*)ln_b)[qb];
            y0.x = fmaf((a0.x - mu) * rs, gA.x, bA.x);
            y0.y = fmaf((a0.y - mu) * rs, gA.y, bA.y);
            y0.z = fmaf((a0.z - mu) * rs, gA.z, bA.z);
            y0.w = fmaf((a0.w - mu) * rs, gA.w, bA.w);
            y1.x = fmaf((a1.x - mu) * rs, gB.x, bB.x);
            y1.y = fmaf((a1.y - mu) * rs, gB.y, bB.y);
            y1.z = fmaf((a1.z - mu) * rs, gB.z, bB.z);
            y1.w = fmaf((a1.w - mu) * rs, gB.w, bB.w);
        }

        // xw[c] = sum_k h[k]*Wg[k][c] for c in 8*dg2..8*dg2+7; h broadcast
        // lazily from the 4-lane group, k ascending (same FP order as ref).
        const float4* __restrict__ W4 = (const float4*)Wgl;
        const int base = lane & ~3;
        #pragma unroll
        for (int s = 0; s < 4; ++s) {
            const float h0 = __shfl(y0.x, base + s, 64);
            const float h1 = __shfl(y0.y, base + s, 64);
            const float h2 = __shfl(y0.z, base + s, 64);
            const float h3 = __shfl(y0.w, base + s, 64);
            const float h4 = __shfl(y1.x, base + s, 64);
            const float h5 = __shfl(y1.y, base + s, 64);
            const float h6 = __shfl(y1.z, base + s, 64);
            const float h7 = __shfl(y1.w, base + s, 64);
            #define GX(J, H) { \
                const float4 wA = W4[(8 * s + (J)) * 8 + qa]; \
                const float4 wB = W4[(8 * s + (J)) * 8 + qb]; \
                o0.x = fmaf(H, wA.x, o0.x); \
                o0.y = fmaf(H, wA.y, o0.y); \
                o0.z = fmaf(H, wA.z, o0.z); \
                o0.w = fmaf(H, wA.w, o0.w); \
                o1.x = fmaf(H, wB.x, o1.x); \
                o1.y = fmaf(H, wB.y, o1.y); \
                o1.z = fmaf(H, wB.z, o1.z); \
                o1.w = fmaf(H, wB.w, o1.w); }
            GX(0, h0) GX(1, h1) GX(2, h2) GX(3, h3)
            GX(4, h4) GX(5, h5) GX(6, h6) GX(7, h7)
            #undef GX
        }

        xwT[8 * dg2 + 0][l] = o0.x;
        xwT[8 * dg2 + 1][l] = o0.y;
        xwT[8 * dg2 + 2][l] = o0.z;
        xwT[8 * dg2 + 3][l] = o0.w;
        xwT[8 * dg2 + 4][l] = o1.x;
        xwT[8 * dg2 + 5][l] = o1.y;
        xwT[8 * dg2 + 6][l] = o1.z;
        xwT[8 * dg2 + 7][l] = o1.w;
    }
    __syncthreads();

    // chain-GCN: out[l] = xw[l]/deg[l] + edge(l-1->l)*xw[l-1]*rsqrt(deg[l-1]deg[l]);
    // gnn = relu(out + b_gcn). deg[0]=1; deg[v>=1] = 1 + (v < valid).
    if (act) {
        const bool hm = (l >= 1) && (l < valid);
        const float degl  = 1.f + ((l >= 1 && l < valid) ? 1.f : 0.f);
        const float deglm = 1.f + ((l - 1 >= 1 && (l - 1) < valid) ? 1.f : 0.f);
        const float invd  = 1.f / degl;
        const float invn  = hm ? rsqrtf(deglm * degl) : 0.f;
        const int lm = hm ? (l - 1) : l;
        const float4 bgA = ((const float4*)b_gcn)[qa];
        const float4 bgB = ((const float4*)b_gcn)[qb];
        float m;
        m = hm ? xwT[8 * dg2 + 0][lm] * invn : 0.f;
        o0.x = fmaxf(fmaf(o0.x, invd, m) + bgA.x, 0.f);
        m = hm ? xwT[8 * dg2 + 1][lm] * invn : 0.f;
        o0.y = fmaxf(fmaf(o0.y, invd, m) + bgA.y, 0.f);
        m = hm ? xwT[8 * dg2 + 2][lm] * invn : 0.f;
        o0.z = fmaxf(fmaf(o0.z, invd, m) + bgA.z, 0.f);
        m = hm ? xwT[8 * dg2 + 3][lm] * invn : 0.f;
        o0.w = fmaxf(fmaf(o0.w, invd, m) + bgA.w, 0.f);
        m = hm ? xwT[8 * dg2 + 4][lm] * invn : 0.f;
        o1.x = fmaxf(fmaf(o1.x, invd, m) + bgB.x, 0.f);
        m = hm ? xwT[8 * dg2 + 5][lm] * invn : 0.f;
        o1.y = fmaxf(fmaf(o1.y, invd, m) + bgB.y, 0.f);
        m = hm ? xwT[8 * dg2 + 6][lm] * invn : 0.f;
        o1.z = fmaxf(fmaf(o1.z, invd, m) + bgB.z, 0.f);
        m = hm ? xwT[8 * dg2 + 7][lm] * invn : 0.f;
        o1.w = fmaxf(fmaf(o1.w, invd, m) + bgB.w, 0.f);
    }
    __syncthreads();   // all xwT reads done before overwrite (WAR)

    if (act) {
        xwT[8 * dg2 + 0][l] = o0.x;
        xwT[8 * dg2 + 1][l] = o0.y;
        xwT[8 * dg2 + 2][l] = o0.z;
        xwT[8 * dg2 + 3][l] = o0.w;
        xwT[8 * dg2 + 4][l] = o1.x;
        xwT[8 * dg2 + 5][l] = o1.y;
        xwT[8 * dg2 + 6][l] = o1.z;
        xwT[8 * dg2 + 7][l] = o1.w;
    }
    __syncthreads();

    // global_mean_pool over L=100 (32 lanes, reads (5t+j)%32: conflict-free)
    if (t < 32) {
        float s = 0.f;
        for (int j = 0; j < 100; ++j) s += xwT[t][j];
        pooled[t] = s * 0.01f;
    }
    __syncthreads();

    if (t < 32) {
        float s = b_out[t];
        #pragma unroll 8
        for (int k = 0; k < 32; ++k) s = fmaf(pooled[k], Wol[k * 32 + t], s);
        out[(size_t)b * 32 + t] = s;                       // src_emb
    } else if (t < 64) {
        const int d = t - 32;
        const __half* fr = feat + (size_t)dst_ids[b] * 32; // broadcast reads
        float s = b_out[d];
        #pragma unroll 8
        for (int k = 0; k < 32; ++k)
            s = fmaf(__half2float(fr[k]), Wol[k * 32 + d], s);
        out[(size_t)B * 32 + (size_t)b * 32 + d] = s;      // dst_emb
    }
}

// ---------------------------------------------------------------------------
extern "C" void kernel_launch(void* const* d_in, const int* in_sizes, int n_in,
                              void* d_out, int out_size, void* d_ws, size_t ws_size,
                              hipStream_t stream)
{
    const float* X      = (const float*)d_in[0];   // [N,128]
    const int*   rnodes = (const int*)  d_in[1];   // [P,100]
    const int*   ridx   = (const int*)  d_in[2];   // [B,5]
    /* d_in[3] src_node_ids: unused by reference */
    const int*   dst    = (const int*)  d_in[4];   // [B]
    /* d_in[5] node_interact_times: unused */
    const float* Wf  = (const float*)d_in[6];
    const float* bf  = (const float*)d_in[7];
    const float* wst = (const float*)d_in[8];
    const float* bst = (const float*)d_in[9];
    const float* lg  = (const float*)d_in[10];
    const float* lb  = (const float*)d_in[11];
    const float* Wg  = (const float*)d_in[12];
    const float* bg  = (const float*)d_in[13];
    const float* Wo  = (const float*)d_in[14];
    const float* bo  = (const float*)d_in[15];

    const int N = in_sizes[0] / 128;   // 100000
    const int B = in_sizes[4];         // 1024

    // workspace: feat_all [N,32] fp16 (6.4MB) | skill [N] i32 (16B-aligned)
    __half* feat = (__half*)d_ws;
    size_t feat_bytes = (((size_t)N * 32 * sizeof(__half)) + 15) & ~(size_t)15;
    int* skill = (int*)((char*)d_ws + feat_bytes);
    float* out = (float*)d_out;

    const int half = (N + 1) >> 1;
    k_feat<<<(half * 8 + 255) / 256, 256, 0, stream>>>(X, Wf, bf, feat, skill, N);
    k_fused<<<B, 512, 0, stream>>>(feat, skill, rnodes, ridx, dst,
                                   wst, bst, lg, lb, Wg, bg, Wo, bo, out, B);
}